// Round 4
// baseline (177.107 us; speedup 1.0000x reference)
//
#include <hip/hip_runtime.h>
#include <hip/hip_bf16.h>

#define Bsz  4096
#define Tn   256
#define CIN  16
#define NCLS 10
#define MB   16          // full 16-row MFMA tile per block

typedef __attribute__((ext_vector_type(8))) short short8;
typedef __attribute__((ext_vector_type(4))) float f32x4;

#if __has_builtin(__builtin_amdgcn_exp2f)
#define EXP2F(x) __builtin_amdgcn_exp2f(x)
#else
#define EXP2F(x) exp2f(x)
#endif
#define RCPF(x) __builtin_amdgcn_rcpf(x)

#define LOG2E 1.442695041f

__device__ inline ushort f2bf(float f) {
    union { float f; unsigned u; } x; x.f = f;
    return (ushort)((x.u + 0x7FFF + ((x.u >> 16) & 1)) >> 16);  // RNE
}

// 12 waves: 0-7 gate (ub = wave&3 -> units 16ub..16ub+15; jh = wave>>2 -> acc rows
// jh*2, jh*2+1 of each grp-quad), 8-11 head. 3 waves/SIMD.
__global__ __launch_bounds__(768, 3) void dualrnn_kernel(
    const float* __restrict__ x,  const float* __restrict__ Wl, const float* __restrict__ bl,
    const float* __restrict__ Wc, const float* __restrict__ bc,
    const float* __restrict__ Wd, const float* __restrict__ bd,
    float* __restrict__ out)
{
    // double-buffered: [parity][batch_row][k]; k: 0..15 x, 16..79 h, 80..95 pad(0)
    __shared__ alignas(16) ushort comb[2][16][104];
    const int tid  = threadIdx.x;
    const int wave = tid >> 6;
    const int lane = tid & 63;
    const int col  = lane & 15;
    const int grp  = lane >> 4;
    const int b0   = blockIdx.x * MB;
    const bool gatew = (wave < 8);

    for (int i = tid; i < 2 * 16 * 104; i += 768) ((ushort*)comb)[i] = 0;

    // ---- preload weights (role-specific, loop-invariant in VGPRs) ----
    // gates: fold exp2 scale; sigmoid gates i,f,o: -log2(e); tanh gate g: +2*log2(e).
    // bias folded into the MFMA C-operand (biasv).
    short8 wf[4][3]; f32x4 biasv[4];
    short8 wcd[2];   f32x4 bcdv;
    const int ub = wave & 3;          // gate waves: unit block
    const int jh = (wave >> 2) & 1;   // gate waves: j-half (0: j=0,1; 1: j=2,3)
    if (gatew) {
#pragma unroll
        for (int g = 0; g < 4; ++g) {
            const float sc = (g == 3) ? 2.f * LOG2E : -LOG2E;
            const int R = g * 64 + ub * 16 + col;
            const float bv = bl[R] * sc;
            biasv[g] = (f32x4){bv, bv, bv, bv};
#pragma unroll
            for (int kt = 0; kt < 3; ++kt)
#pragma unroll
                for (int i = 0; i < 8; ++i) {
                    const int k = kt * 32 + grp * 8 + i;
                    wf[g][kt][i] = (short)f2bf(k < 80 ? Wl[R * 80 + k] * sc : 0.f);
                }
        }
    } else {
        // class lanes (col<10): natural scale. dec lane (col==10): fold -log2(e).
#pragma unroll
        for (int kt = 0; kt < 2; ++kt)
#pragma unroll
            for (int i = 0; i < 8; ++i) {
                const int k = kt * 32 + grp * 8 + i;
                float v = 0.f;
                if (col < 10)       v = Wc[col * 64 + k];
                else if (col == 10) v = Wd[k] * -LOG2E;
                wcd[kt][i] = (short)f2bf(v);
            }
        const float bv = (col < 10) ? bc[col] : ((col == 10) ? bd[0] * -LOG2E : 0.f);
        bcdv = (f32x4){bv, bv, bv, bv};
    }

    __syncthreads();   // zeroing done before x_0 write (avoid zero/x race)

    if (tid < 256) {   // x_0 into comb[0]; h-section stays zero
        const int r = tid >> 4, ch = tid & 15;
        comb[0][r][ch] = f2bf(x[((size_t)(b0 + r) * Tn) * CIN + ch]);
    }
    __syncthreads();

    float cst[2] = {0, 0};   // c state (gate waves): rows grp*4 + jh*2 + jj, unit 16*ub+col
    float pnd = 1.f;         // head waves, lanes col==10, row grp*4+hw

    const int hw  = wave & 3;            // head-wave id 0..3
    const int row = grp * 4 + hw;        // output row this head thread owns (slot j==hw)
    float* lp_p = out + ((size_t)(b0 + row) * Tn) * NCLS + col;              // [B][T][10]
    float* pt_p = out + (size_t)Bsz * Tn * NCLS + (size_t)(b0 + row) * Tn;   // [B][T]
    const int t2 = hw * 64 + lane;       // 0..255 across head waves
    const int xr = t2 >> 4, xc = t2 & 15;
    // 2-deep x prefetch: xva holds x_{t+1} (written this iter); load x_{t+2} now.
    float xva = 0.f;
    const float* xp = x + ((size_t)(b0 + xr) * Tn + 2) * CIN + xc;
    if (!gatew) xva = x[((size_t)(b0 + xr) * Tn + 1) * CIN + xc];

    // iter t: read comb[t&1] = {x_t, h_{t-1}}; gates write h_t, head writes x_{t+1}
    // into comb[(t+1)&1]; head outputs step t-1 from h_{t-1}. One barrier/iter.
    for (int t = 0; t < Tn; ++t) {
        const ushort (*rdb)[104] = comb[t & 1];
        ushort (*wrb)[104] = comb[(t + 1) & 1];
        if (gatew) {
            const short8 a0 = *(const short8*)&rdb[col][ 0 + grp * 8];
            const short8 a1 = *(const short8*)&rdb[col][32 + grp * 8];
            const short8 a2 = *(const short8*)&rdb[col][64 + grp * 8];
            __builtin_amdgcn_s_setprio(1);
            f32x4 acc[4];
#pragma unroll
            for (int g = 0; g < 4; ++g) {
                f32x4 z = biasv[g];
                z = __builtin_amdgcn_mfma_f32_16x16x32_bf16(a0, wf[g][0], z, 0, 0, 0);
                z = __builtin_amdgcn_mfma_f32_16x16x32_bf16(a1, wf[g][1], z, 0, 0, 0);
                z = __builtin_amdgcn_mfma_f32_16x16x32_bf16(a2, wf[g][2], z, 0, 0, 0);
                acc[g] = z;
            }
            __builtin_amdgcn_s_setprio(0);
            const int hc = 16 + ub * 16 + col;
#pragma unroll
            for (int jj = 0; jj < 2; ++jj) {
                // compile-time lane extraction (avoid runtime-indexed ext_vector)
                const float av_i = jh ? acc[0][jj + 2] : acc[0][jj];
                const float av_f = jh ? acc[1][jj + 2] : acc[1][jj];
                const float av_o = jh ? acc[2][jj + 2] : acc[2][jj];
                const float av_g = jh ? acc[3][jj + 2] : acc[3][jj];
                // gi=1/A, gf=1/B, tanh_g=G2/G1, go=1/O
                const float ei = EXP2F(av_i);
                const float ef = EXP2F(av_f);
                const float eo = EXP2F(av_o);
                const float eg = EXP2F(av_g);
                const float A  = 1.f + ei, Bv = 1.f + ef;
                const float G1 = eg + 1.f, G2 = eg - 1.f, O = 1.f + eo;
                const float t0  = A * G1;
                const float num = cst[jj] * t0 + G2 * Bv;
                const float den = Bv * t0;
                const float cn  = num * RCPF(den);
                cst[jj] = cn;
                const float e2 = EXP2F(2.f * LOG2E * cn);
                const float h  = (e2 - 1.f) * RCPF((e2 + 1.f) * O);
                wrb[grp * 4 + jh * 2 + jj][hc] = f2bf(h);
            }
        } else {
            // issue x_{t+2} load first (covered by this whole step)
            float xvn = 0.f;
            if (t + 2 < Tn) xvn = *xp;
            xp += CIN;
            const short8 ha0 = *(const short8*)&rdb[col][16 + grp * 8];
            const short8 ha1 = *(const short8*)&rdb[col][48 + grp * 8];
            f32x4 cz = bcdv;
            cz = __builtin_amdgcn_mfma_f32_16x16x32_bf16(ha0, wcd[0], cz, 0, 0, 0);
            cz = __builtin_amdgcn_mfma_f32_16x16x32_bf16(ha1, wcd[1], cz, 0, 0, 0);
            if (t + 1 < Tn) wrb[xr][xc] = f2bf(xva);   // x_{t+1}, loaded LAST iter
            xva = xvn;
            if (t > 0) {
                float v = (hw & 1) ? ((hw & 2) ? cz[3] : cz[1])
                                   : ((hw & 2) ? cz[2] : cz[0]);
                // |logits| small -> skip max-subtraction; sum exp over 16-lane group
                float s = (col < 10) ? EXP2F(v * LOG2E) : 0.f;
                s += __int_as_float(__builtin_amdgcn_ds_swizzle(__float_as_int(s), 0x041F));
                s += __int_as_float(__builtin_amdgcn_ds_swizzle(__float_as_int(s), 0x081F));
                s += __int_as_float(__builtin_amdgcn_ds_swizzle(__float_as_int(s), 0x101F));
                s += __int_as_float(__builtin_amdgcn_ds_swizzle(__float_as_int(s), 0x201F));
                const float lse = __logf(s);
                if (col < 10) {
                    lp_p[0] = v - lse;
                } else if (col == 10) {
                    const float d = RCPF(1.f + EXP2F(v));   // -log2e folded in wcd
                    pt_p[0] = d * pnd;
                    pnd *= (1.f - d);
                }
                lp_p += NCLS;
                pt_p += 1;
            }
        }
        __syncthreads();
    }

    // epilogue: output step Tn-1 from h_{Tn-1} in comb[Tn&1]
    if (!gatew) {
        const ushort (*rdb)[104] = comb[Tn & 1];
        const short8 ha0 = *(const short8*)&rdb[col][16 + grp * 8];
        const short8 ha1 = *(const short8*)&rdb[col][48 + grp * 8];
        f32x4 cz = bcdv;
        cz = __builtin_amdgcn_mfma_f32_16x16x32_bf16(ha0, wcd[0], cz, 0, 0, 0);
        cz = __builtin_amdgcn_mfma_f32_16x16x32_bf16(ha1, wcd[1], cz, 0, 0, 0);
        float v = (hw & 1) ? ((hw & 2) ? cz[3] : cz[1])
                           : ((hw & 2) ? cz[2] : cz[0]);
        float s = (col < 10) ? EXP2F(v * LOG2E) : 0.f;
        s += __int_as_float(__builtin_amdgcn_ds_swizzle(__float_as_int(s), 0x041F));
        s += __int_as_float(__builtin_amdgcn_ds_swizzle(__float_as_int(s), 0x081F));
        s += __int_as_float(__builtin_amdgcn_ds_swizzle(__float_as_int(s), 0x101F));
        s += __int_as_float(__builtin_amdgcn_ds_swizzle(__float_as_int(s), 0x201F));
        const float lse = __logf(s);
        if (col < 10)       lp_p[0] = v - lse;
        else if (col == 10) pt_p[0] = pnd;   // is_last: Pt = pnd_{T-1}
    }
}

extern "C" void kernel_launch(void* const* d_in, const int* in_sizes, int n_in,
                              void* d_out, int out_size, void* d_ws, size_t ws_size,
                              hipStream_t stream) {
    const float* x  = (const float*)d_in[0];
    const float* Wl = (const float*)d_in[1];
    const float* bl = (const float*)d_in[2];
    const float* Wc = (const float*)d_in[3];
    const float* bc = (const float*)d_in[4];
    const float* Wd = (const float*)d_in[5];
    const float* bd = (const float*)d_in[6];
    float* out = (float*)d_out;

    dim3 grid(Bsz / MB), block(768);
    hipLaunchKernelGGL(dualrnn_kernel, grid, block, 0, stream,
                       x, Wl, bl, Wc, bc, Wd, bd, out);
}